// Round 4
// baseline (272.849 us; speedup 1.0000x reference)
//
#include <hip/hip_runtime.h>

#define BB 512
#define LL 128
#define MM 127
#define EPS 1e-5f

typedef _Float16 half4 __attribute__((ext_vector_type(4)));
typedef _Float16 half8 __attribute__((ext_vector_type(8)));
typedef float f32x16 __attribute__((ext_vector_type(16)));

// hb layout: per batch b: 128 rows x 192 ch fp16, row pitch 384 B,
// in-row byte offset = (2*ch) ^ ((row&7)<<4)   (XOR swizzle, G4)
#define HB_PITCH 384
#define HB_BATCH 49152

// ---------------------------------------------------------------- K0: weight prep
// blocks 0..31: lwT[col][k] fp16 swizzled (lin1_w transpose).
// block 32:     ewT[col][k] fp16 swizzled; cols 0..127 = wd = top-bot, 128..255 = wb = bot.
__global__ __launch_bounds__(256) void k0_prep(
    const float* __restrict__ lw, char* __restrict__ lwT,
    const float* __restrict__ ew, char* __restrict__ ewT)
{
  int tid = threadIdx.x;
  if (blockIdx.x < 32) {
    int c0 = blockIdx.x * 32;
    __shared__ float wcol[192][32];
    for (int i = tid; i < 192 * 32; i += 256) {
      int k = i >> 5, c = i & 31;
      wcol[k][c] = lw[k * 1024 + c0 + c];
    }
    __syncthreads();
    for (int j = tid; j < 768; j += 256) {
      int kg = j >> 5, c = j & 31;
      half8 v;
#pragma unroll
      for (int jj = 0; jj < 8; jj++) v[jj] = (_Float16)wcol[kg * 8 + jj][c];
      int cc = c0 + c;
      *(half8*)(lwT + cc * HB_PITCH + ((kg * 16) ^ ((cc & 7) << 4))) = v;
    }
  } else {
    __shared__ float es[128][128];   // ew is 128x128 f32
    for (int i = tid; i < 128 * 128; i += 256) es[i >> 7][i & 127] = ew[i];
    __syncthreads();
    for (int i = tid; i < 256 * 8; i += 256) {
      int c = i >> 3, kg = i & 7;
      half8 v;
#pragma unroll
      for (int jj = 0; jj < 8; jj++) {
        int k = kg * 8 + jj;
        float val = (c < 128) ? (es[k][c] - es[64 + k][c]) : es[64 + k][c - 128];
        v[jj] = (_Float16)val;
      }
      *(half8*)(ewT + c * 128 + ((kg * 16) ^ ((c & 7) << 4))) = v;
    }
  }
}

// ---------------------------------------------------------------- K1: conv1d
__global__ __launch_bounds__(256) void k1_conv(
    const float* __restrict__ pos, const float* __restrict__ cw,
    const float* __restrict__ cb, const float* __restrict__ g1,
    const float* __restrict__ b1, const float* __restrict__ m1,
    const float* __restrict__ v1, float* __restrict__ xg,
    char* __restrict__ hb)
{
  int b = blockIdx.x;
  int tid = threadIdx.x;
  __shared__ float ps[LL * 3];
  __shared__ float fpad[MM + 4][6];
  __shared__ float ws[5 * 6 * 64];
  __shared__ float s1s[64], t1s[64];
  for (int i = tid; i < LL * 3; i += 256) ps[i] = pos[b * LL * 3 + i];
  for (int i = tid; i < 5 * 6 * 64; i += 256) ws[i] = cw[i];
  if (tid < 64) {
    float s = g1[tid] * rsqrtf(v1[tid] + EPS);
    s1s[tid] = s;
    t1s[tid] = (cb[tid] - m1[tid]) * s + b1[tid];
  }
  if (tid < 24) {
    int r = tid / 6, c = tid % 6;
    int rr = (r < 2) ? r : (MM + r);
    fpad[rr][c] = 0.f;
  }
  __syncthreads();
  for (int i = tid; i < MM * 6; i += 256) {
    int m = i / 6, c = i % 6;
    float v = (c < 3) ? (ps[(m + 1) * 3 + c] - ps[m * 3 + c]) : ps[m * 3 + c - 3];
    fpad[m + 2][c] = v;
  }
  __syncthreads();
  int orow = BB - 1 - b;
  char* hbb = hb + (size_t)orow * HB_BATCH;
  // zero fp16 pad row 127, ch 0..63 region (bytes [0,128))
  if (tid < 8) *(float4*)(hbb + 127 * HB_PITCH + tid * 16) = make_float4(0.f, 0.f, 0.f, 0.f);
  for (int o = tid; o < MM * 64; o += 256) {
    int m = o >> 6, c = o & 63;
    float af = 0.f, ab = 0.f;
#pragma unroll
    for (int t = 0; t < 5; t++) {
#pragma unroll
      for (int ci = 0; ci < 6; ci++) {
        float wv = ws[(t * 6 + ci) * 64 + c];
        af = fmaf(fpad[m + t][ci], wv, af);
        ab = fmaf(fpad[m + 4 - t][ci], wv, ab);
      }
    }
    float z = fmaxf(af, ab) * s1s[c] + t1s[c];
    float xv = fmaxf(z, 0.f);
    int p = MM - 1 - m;
    xg[(orow * MM + p) * 64 + c] = xv;
    *(_Float16*)(hbb + p * HB_PITCH + ((2 * c) ^ ((p & 7) << 4))) = (_Float16)xv;
  }
}

// ---------------------------------------------------------------- K2: kNN top-5
__global__ __launch_bounds__(128) void k2_knn(
    const float* __restrict__ xg, int* __restrict__ idxb)
{
  int b = blockIdx.x;
  int tid = threadIdx.x;
  __shared__ float xs[MM][64];
  __shared__ float sq[MM];
  const float* src = xg + b * MM * 64;
  for (int i = tid; i < MM * 64; i += 128) xs[i >> 6][i & 63] = src[i];
  __syncthreads();
  float xm[64];
  if (tid < MM) {
    float s = 0.f;
#pragma unroll
    for (int d = 0; d < 64; d++) { xm[d] = xs[tid][d]; s = fmaf(xm[d], xm[d], s); }
    sq[tid] = s;
  }
  __syncthreads();
  if (tid < MM) {
    float bs[5]; int bi[5];
#pragma unroll
    for (int k = 0; k < 5; k++) { bs[k] = 1e30f; bi[k] = 0; }
    for (int j = 0; j < MM; j++) {
      float dot = 0.f;
#pragma unroll
      for (int d = 0; d < 64; d++) dot = fmaf(xm[d], xs[j][d], dot);
      float sc = sq[j] - 2.f * dot;
      if (sc < bs[4]) {
        bs[4] = sc; bi[4] = j;
#pragma unroll
        for (int k = 3; k >= 0; k--) {
          if (bs[k + 1] < bs[k]) {
            float ts = bs[k]; bs[k] = bs[k + 1]; bs[k + 1] = ts;
            int ti = bi[k]; bi[k] = bi[k + 1]; bi[k + 1] = ti;
          }
        }
      }
    }
    int base = (b * MM + tid) * 5;
#pragma unroll
    for (int k = 0; k < 5; k++) idxb[base + k] = bi[k];
  }
}

// ---------------------------------------------------------------- K3: edge MLP via MFMA
__global__ __launch_bounds__(256) void k3_edge(
    const int* __restrict__ idxb, const char* __restrict__ ewT,
    const float* __restrict__ eb, const float* __restrict__ g2,
    const float* __restrict__ b2, const float* __restrict__ m2,
    const float* __restrict__ v2, char* __restrict__ hb)
{
  int b = blockIdx.x;
  int tid = threadIdx.x;
  int w = tid >> 6, l = tid & 63;
  int lo = l & 31, hi = l >> 5;
  __shared__ _Float16 vvs[MM][136];   // pitch 272 B (68 dw == 4 mod 32: rows shift banks)
  __shared__ int idxs[MM * 5];
  char* hbb = hb + (size_t)b * HB_BATCH;

  for (int i = tid; i < MM * 5; i += 256) idxs[i] = idxb[b * MM * 5 + i];
  // zero pad row 127, ch 64..191 (bytes [128,384)) for k4
  if (tid < 16) *(float4*)(hbb + 127 * HB_PITCH + 128 + tid * 16) = make_float4(0.f, 0.f, 0.f, 0.f);

  half8 af[4][4];
#pragma unroll
  for (int rt = 0; rt < 4; rt++) {
    int row = rt * 32 + lo;
    const char* rb = hbb + row * HB_PITCH;
    int sz = (row & 7) << 4;
#pragma unroll
    for (int ks = 0; ks < 4; ks++)
      af[rt][ks] = *(const half8*)(rb + ((ks * 32 + hi * 16) ^ sz));
  }
  int cu = w * 32 + lo;
  int swzW = (cu & 7) << 4;
  const char* wu = ewT + cu * 128;
  const char* wv = ewT + (128 + cu) * 128;
  half8 bu[4], bv[4];
#pragma unroll
  for (int ks = 0; ks < 4; ks++) {
    int off = (ks * 32 + hi * 16) ^ swzW;
    bu[ks] = *(const half8*)(wu + off);
    bv[ks] = *(const half8*)(wv + off);
  }
  f32x16 accu[4], accv[4];
#pragma unroll
  for (int rt = 0; rt < 4; rt++)
#pragma unroll
    for (int r = 0; r < 16; r++) { accu[rt][r] = 0.f; accv[rt][r] = 0.f; }
#pragma unroll
  for (int ks = 0; ks < 4; ks++)
#pragma unroll
    for (int rt = 0; rt < 4; rt++) {
      accu[rt] = __builtin_amdgcn_mfma_f32_32x32x16_f16(af[rt][ks], bu[ks], accu[rt], 0, 0, 0);
      accv[rt] = __builtin_amdgcn_mfma_f32_32x32x16_f16(af[rt][ks], bv[ks], accv[rt], 0, 0, 0);
    }
#pragma unroll
  for (int rt = 0; rt < 4; rt++)
#pragma unroll
    for (int r = 0; r < 16; r++) {
      int p = rt * 32 + (r & 3) + 8 * (r >> 2) + 4 * hi;
      if (p < MM) vvs[p][cu] = (_Float16)accv[rt][r];
    }
  __syncthreads();
  float ebv = eb[cu];
  float s2 = g2[cu] * rsqrtf(v2[cu] + EPS);
  float t2 = b2[cu] - m2[cu] * s2;
#pragma unroll
  for (int rt = 0; rt < 4; rt++)
#pragma unroll
    for (int r = 0; r < 16; r++) {
      int p = rt * 32 + (r & 3) + 8 * (r >> 2) + 4 * hi;
      if (p >= MM) continue;
      const int* ip = &idxs[p * 5];
      float u = accu[rt][r];
      float mx = -1e30f;
#pragma unroll
      for (int k = 0; k < 5; k++)
        mx = fmaxf(mx, u + (float)vvs[ip[k]][cu]);
      float o = fmaxf(mx + ebv, 0.f) * s2 + t2;
      *(_Float16*)(hbb + p * HB_PITCH + ((128 + 2 * cu) ^ ((p & 7) << 4))) = (_Float16)o;
    }
}

// ---------------------------------------------------------------- K4: lin1 via MFMA + max over M
// v3: 512 threads / 8 waves, wave w owns 128-col chunk w (4 col-tiles of 32).
// LDS = A only (48 KB). B-frags read DIRECT from global lwT (L2-resident),
// register double-buffered one col-tile ahead. rt accumulated in 2 pairs
// (acc[2], 32 regs) with running row-max rm folded between pairs -> ~<210 VGPR
// -> 2 waves/SIMD. No barriers in main loop.
__global__ __launch_bounds__(512, 2) void k4_lin1(
    const char* __restrict__ hb, const char* __restrict__ lwT,
    const float* __restrict__ lb, const float* __restrict__ g3,
    const float* __restrict__ b3, const float* __restrict__ m3,
    const float* __restrict__ v3, float* __restrict__ gout)
{
  int b = blockIdx.x;
  int tid = threadIdx.x;
  int w = tid >> 6, l = tid & 63;
  int lo = l & 31, hi = l >> 5;
  __shared__ __align__(16) char sA[HB_BATCH];   // 48 KB

  {
    const char* gA = hb + (size_t)b * HB_BATCH;
#pragma unroll
    for (int i = 0; i < 6; i++)
      *(float4*)(sA + (i * 512 + tid) * 16) = *(const float4*)(gA + (i * 512 + tid) * 16);
  }
  __syncthreads();

  // A-fragments: row = rt*32+lo, k bytes (ks*32 + hi*16) ^ ((row&7)<<4)
  half8 af[4][12];
  int sz = (lo & 7) << 4;
#pragma unroll
  for (int rt = 0; rt < 4; rt++) {
    const char* rbase = sA + (rt * 32 + lo) * HB_PITCH;
#pragma unroll
    for (int ks = 0; ks < 12; ks++)
      af[rt][ks] = *(const half8*)(rbase + ((ks * 32 + hi * 16) ^ sz));
  }

  int col0 = w * 128 + lo;           // this wave's first col-tile column
  half8 bf[2][12];
  {
    const char* cb0 = lwT + (size_t)col0 * HB_PITCH;
#pragma unroll
    for (int ks = 0; ks < 12; ks++)
      bf[0][ks] = *(const half8*)(cb0 + ((ks * 32 + hi * 16) ^ sz));
  }
#pragma unroll
  for (int ct = 0; ct < 4; ct++) {
    // prefetch next col-tile's B-frags (hides L2 latency under MFMAs)
    if (ct < 3) {
      const char* cbn = lwT + (size_t)(col0 + (ct + 1) * 32) * HB_PITCH;
#pragma unroll
      for (int ks = 0; ks < 12; ks++)
        bf[(ct + 1) & 1][ks] = *(const half8*)(cbn + ((ks * 32 + hi * 16) ^ sz));
    }
    float rm = 0.f;
    int col = col0 + ct * 32;
    float bias = lb[col];
#pragma unroll
    for (int pr = 0; pr < 2; pr++) {
      f32x16 acc[2];
#pragma unroll
      for (int q = 0; q < 2; q++)
#pragma unroll
        for (int r = 0; r < 16; r++) acc[q][r] = 0.f;
#pragma unroll
      for (int ks = 0; ks < 12; ks++) {
        acc[0] = __builtin_amdgcn_mfma_f32_32x32x16_f16(af[pr * 2][ks], bf[ct & 1][ks], acc[0], 0, 0, 0);
        acc[1] = __builtin_amdgcn_mfma_f32_32x32x16_f16(af[pr * 2 + 1][ks], bf[ct & 1][ks], acc[1], 0, 0, 0);
      }
#pragma unroll
      for (int q = 0; q < 2; q++)
#pragma unroll
        for (int r = 0; r < 16; r++) {
          float v = fmaxf(acc[q][r] + bias, 0.f);
          if (pr == 1 && q == 1 && r == 15) v = hi ? 0.f : v;  // global row 127 = pad
          rm = fmaxf(rm, v);
        }
    }
    rm = fmaxf(rm, __shfl_xor(rm, 32));
    if (hi == 0) {
      float s = g3[col] * rsqrtf(v3[col] + EPS);
      float t = b3[col] - m3[col] * s;
      gout[b * 1024 + col] = rm * s + t;
    }
  }
}

// ---------------------------------------------------------------- K5: head MLP layers
__global__ __launch_bounds__(256) void k5_mlp(
    const float* __restrict__ in, const float* __restrict__ w,
    const float* __restrict__ bias, const float* __restrict__ gg,
    const float* __restrict__ bbp, const float* __restrict__ mmp,
    const float* __restrict__ vvp, float* __restrict__ out,
    int K, int N, int ctiles)
{
  int bid = blockIdx.x;
  int rg = bid / ctiles, ct = bid % ctiles;
  int tid = threadIdx.x;
  int c = tid & 127, rh = tid >> 7;
  int col = ct * 128 + c;
  extern __shared__ float grows[];
  for (int i = tid; i < 4 * K; i += 256) grows[i] = in[rg * 4 * K + i];
  __syncthreads();
  float acc0 = 0.f, acc1 = 0.f;
  for (int d4 = 0; d4 < K / 4; d4++) {
    float4 ga = *reinterpret_cast<const float4*>(&grows[rh * K + d4 * 4]);
    float4 gb = *reinterpret_cast<const float4*>(&grows[(rh + 2) * K + d4 * 4]);
    float gaa[4] = {ga.x, ga.y, ga.z, ga.w};
    float gba[4] = {gb.x, gb.y, gb.z, gb.w};
#pragma unroll
    for (int dd = 0; dd < 4; dd++) {
      float wv = w[(d4 * 4 + dd) * N + col];
      acc0 = fmaf(gaa[dd], wv, acc0);
      acc1 = fmaf(gba[dd], wv, acc1);
    }
  }
  float s = gg[col] * rsqrtf(vvp[col] + EPS);
  float t = bbp[col] - mmp[col] * s;
  float bv = bias[col];
  int r0 = rg * 4;
  out[(r0 + rh) * N + col] = fmaxf(acc0 + bv, 0.f) * s + t;
  out[(r0 + rh + 2) * N + col] = fmaxf(acc1 + bv, 0.f) * s + t;
}

// ---------------------------------------------------------------- K5c: final 256->2
__global__ __launch_bounds__(256) void k5c_out(
    const float* __restrict__ c2, const float* __restrict__ ow,
    const float* __restrict__ ob, float* __restrict__ out)
{
  int t = blockIdx.x * 256 + threadIdx.x;
  int r = t >> 1, c = t & 1;
  float acc = 0.f;
  for (int d = 0; d < 256; d++) acc = fmaf(c2[r * 256 + d], ow[d * 2 + c], acc);
  out[t] = acc + ob[c];
}

extern "C" void kernel_launch(void* const* d_in, const int* in_sizes, int n_in,
                              void* d_out, int out_size, void* d_ws, size_t ws_size,
                              hipStream_t stream)
{
  const float* pos = (const float*)d_in[0];
  const float* cw  = (const float*)d_in[4];
  const float* cb  = (const float*)d_in[5];
  const float* g1  = (const float*)d_in[6];
  const float* b1  = (const float*)d_in[7];
  const float* m1  = (const float*)d_in[8];
  const float* v1  = (const float*)d_in[9];
  const float* ew  = (const float*)d_in[10];
  const float* eb  = (const float*)d_in[11];
  const float* g2  = (const float*)d_in[12];
  const float* b2  = (const float*)d_in[13];
  const float* m2  = (const float*)d_in[14];
  const float* v2  = (const float*)d_in[15];
  const float* lw  = (const float*)d_in[16];
  const float* lb  = (const float*)d_in[17];
  const float* g3  = (const float*)d_in[18];
  const float* b3  = (const float*)d_in[19];
  const float* m3  = (const float*)d_in[20];
  const float* v3  = (const float*)d_in[21];
  const float* m1w = (const float*)d_in[22];
  const float* m1b = (const float*)d_in[23];
  const float* g4  = (const float*)d_in[24];
  const float* b4  = (const float*)d_in[25];
  const float* m4  = (const float*)d_in[26];
  const float* v4  = (const float*)d_in[27];
  const float* m2w = (const float*)d_in[28];
  const float* m2b = (const float*)d_in[29];
  const float* g5  = (const float*)d_in[30];
  const float* b5  = (const float*)d_in[31];
  const float* m5  = (const float*)d_in[32];
  const float* v5  = (const float*)d_in[33];
  const float* ow  = (const float*)d_in[34];
  const float* ob  = (const float*)d_in[35];

  char* ws = (char*)d_ws;
  float* xg   = (float*)(ws);              // 512*127*64 f32      = 16,646,144 B
  char*  hb   = ws + 16646144;             // 512*128*192 f16 swz = 25,165,824 B
  char*  lwT  = ws + 41811968;             // 1024*192 f16 swz    =    393,216 B
  char*  ewT  = ws + 42205184;             // 256*64 f16 swz      =     32,768 B
  int*   idxb = (int*)(ws + 42237952);     // 512*127*5 i32       =  1,300,480 B
  float* gbuf = (float*)(ws + 43538432);   // 512*1024 f32        =  2,097,152 B
  float* c1   = (float*)(ws + 45635584);   // 512*512 f32         =  1,048,576 B
  float* c2   = (float*)(ws + 46684160);   // 512*256 f32         =    524,288 B

  hipLaunchKernelGGL(k0_prep, dim3(33), dim3(256), 0, stream, lw, lwT, ew, ewT);
  hipLaunchKernelGGL(k1_conv, dim3(512), dim3(256), 0, stream,
                     pos, cw, cb, g1, b1, m1, v1, xg, hb);
  hipLaunchKernelGGL(k2_knn, dim3(512), dim3(128), 0, stream, xg, idxb);
  hipLaunchKernelGGL(k3_edge, dim3(512), dim3(256), 0, stream,
                     idxb, ewT, eb, g2, b2, m2, v2, hb);
  hipLaunchKernelGGL(k4_lin1, dim3(512), dim3(512), 0, stream,
                     hb, lwT, lb, g3, b3, m3, v3, gbuf);
  hipLaunchKernelGGL(k5_mlp, dim3(512), dim3(256), 4 * 1024 * 4, stream,
                     gbuf, m1w, m1b, g4, b4, m4, v4, c1, 1024, 512, 4);
  hipLaunchKernelGGL(k5_mlp, dim3(256), dim3(256), 4 * 512 * 4, stream,
                     c1, m2w, m2b, g5, b5, m5, v5, c2, 512, 256, 2);
  hipLaunchKernelGGL(k5c_out, dim3(4), dim3(256), 0, stream,
                     c2, ow, ob, (float*)d_out);
}

// Round 5
// 226.337 us; speedup vs baseline: 1.2055x; 1.2055x over previous
//
#include <hip/hip_runtime.h>

#define BB 512
#define LL 128
#define MM 127
#define EPS 1e-5f

typedef _Float16 half4 __attribute__((ext_vector_type(4)));
typedef _Float16 half8 __attribute__((ext_vector_type(8)));
typedef float f32x16 __attribute__((ext_vector_type(16)));

// hb layout: per batch b: 128 rows x 192 ch fp16, row pitch 384 B,
// in-row byte offset = (2*ch) ^ ((row&7)<<4)   (XOR swizzle, G4)
#define HB_PITCH 384
#define HB_BATCH 49152

// ---------------------------------------------------------------- K0: weight prep
// blocks 0..31: lwT[col][k] fp16 swizzled (lin1_w transpose).
// block 32:     ewT[col][k] fp16 swizzled; cols 0..127 = wd = top-bot, 128..255 = wb = bot.
__global__ __launch_bounds__(256) void k0_prep(
    const float* __restrict__ lw, char* __restrict__ lwT,
    const float* __restrict__ ew, char* __restrict__ ewT)
{
  int tid = threadIdx.x;
  if (blockIdx.x < 32) {
    int c0 = blockIdx.x * 32;
    __shared__ float wcol[192][32];
    for (int i = tid; i < 192 * 32; i += 256) {
      int k = i >> 5, c = i & 31;
      wcol[k][c] = lw[k * 1024 + c0 + c];
    }
    __syncthreads();
    for (int j = tid; j < 768; j += 256) {
      int kg = j >> 5, c = j & 31;
      half8 v;
#pragma unroll
      for (int jj = 0; jj < 8; jj++) v[jj] = (_Float16)wcol[kg * 8 + jj][c];
      int cc = c0 + c;
      *(half8*)(lwT + cc * HB_PITCH + ((kg * 16) ^ ((cc & 7) << 4))) = v;
    }
  } else {
    __shared__ float es[128][128];   // ew is 128x128 f32
    for (int i = tid; i < 128 * 128; i += 256) es[i >> 7][i & 127] = ew[i];
    __syncthreads();
    for (int i = tid; i < 256 * 8; i += 256) {
      int c = i >> 3, kg = i & 7;
      half8 v;
#pragma unroll
      for (int jj = 0; jj < 8; jj++) {
        int k = kg * 8 + jj;
        float val = (c < 128) ? (es[k][c] - es[64 + k][c]) : es[64 + k][c - 128];
        v[jj] = (_Float16)val;
      }
      *(half8*)(ewT + c * 128 + ((kg * 16) ^ ((c & 7) << 4))) = v;
    }
  }
}

// ---------------------------------------------------------------- K1: conv1d
__global__ __launch_bounds__(256) void k1_conv(
    const float* __restrict__ pos, const float* __restrict__ cw,
    const float* __restrict__ cb, const float* __restrict__ g1,
    const float* __restrict__ b1, const float* __restrict__ m1,
    const float* __restrict__ v1, float* __restrict__ xg,
    char* __restrict__ hb)
{
  int b = blockIdx.x;
  int tid = threadIdx.x;
  __shared__ float ps[LL * 3];
  __shared__ float fpad[MM + 4][6];
  __shared__ float ws[5 * 6 * 64];
  __shared__ float s1s[64], t1s[64];
  for (int i = tid; i < LL * 3; i += 256) ps[i] = pos[b * LL * 3 + i];
  for (int i = tid; i < 5 * 6 * 64; i += 256) ws[i] = cw[i];
  if (tid < 64) {
    float s = g1[tid] * rsqrtf(v1[tid] + EPS);
    s1s[tid] = s;
    t1s[tid] = (cb[tid] - m1[tid]) * s + b1[tid];
  }
  if (tid < 24) {
    int r = tid / 6, c = tid % 6;
    int rr = (r < 2) ? r : (MM + r);
    fpad[rr][c] = 0.f;
  }
  __syncthreads();
  for (int i = tid; i < MM * 6; i += 256) {
    int m = i / 6, c = i % 6;
    float v = (c < 3) ? (ps[(m + 1) * 3 + c] - ps[m * 3 + c]) : ps[m * 3 + c - 3];
    fpad[m + 2][c] = v;
  }
  __syncthreads();
  int orow = BB - 1 - b;
  char* hbb = hb + (size_t)orow * HB_BATCH;
  // zero fp16 pad row 127, ch 0..63 region (bytes [0,128))
  if (tid < 8) *(float4*)(hbb + 127 * HB_PITCH + tid * 16) = make_float4(0.f, 0.f, 0.f, 0.f);
  for (int o = tid; o < MM * 64; o += 256) {
    int m = o >> 6, c = o & 63;
    float af = 0.f, ab = 0.f;
#pragma unroll
    for (int t = 0; t < 5; t++) {
#pragma unroll
      for (int ci = 0; ci < 6; ci++) {
        float wv = ws[(t * 6 + ci) * 64 + c];
        af = fmaf(fpad[m + t][ci], wv, af);
        ab = fmaf(fpad[m + 4 - t][ci], wv, ab);
      }
    }
    float z = fmaxf(af, ab) * s1s[c] + t1s[c];
    float xv = fmaxf(z, 0.f);
    int p = MM - 1 - m;
    xg[(orow * MM + p) * 64 + c] = xv;
    *(_Float16*)(hbb + p * HB_PITCH + ((2 * c) ^ ((p & 7) << 4))) = (_Float16)xv;
  }
}

// ---------------------------------------------------------------- K2: kNN top-5
__global__ __launch_bounds__(128) void k2_knn(
    const float* __restrict__ xg, int* __restrict__ idxb)
{
  int b = blockIdx.x;
  int tid = threadIdx.x;
  __shared__ float xs[MM][64];
  __shared__ float sq[MM];
  const float* src = xg + b * MM * 64;
  for (int i = tid; i < MM * 64; i += 128) xs[i >> 6][i & 63] = src[i];
  __syncthreads();
  float xm[64];
  if (tid < MM) {
    float s = 0.f;
#pragma unroll
    for (int d = 0; d < 64; d++) { xm[d] = xs[tid][d]; s = fmaf(xm[d], xm[d], s); }
    sq[tid] = s;
  }
  __syncthreads();
  if (tid < MM) {
    float bs[5]; int bi[5];
#pragma unroll
    for (int k = 0; k < 5; k++) { bs[k] = 1e30f; bi[k] = 0; }
    for (int j = 0; j < MM; j++) {
      float dot = 0.f;
#pragma unroll
      for (int d = 0; d < 64; d++) dot = fmaf(xm[d], xs[j][d], dot);
      float sc = sq[j] - 2.f * dot;
      if (sc < bs[4]) {
        bs[4] = sc; bi[4] = j;
#pragma unroll
        for (int k = 3; k >= 0; k--) {
          if (bs[k + 1] < bs[k]) {
            float ts = bs[k]; bs[k] = bs[k + 1]; bs[k + 1] = ts;
            int ti = bi[k]; bi[k] = bi[k + 1]; bi[k + 1] = ti;
          }
        }
      }
    }
    int base = (b * MM + tid) * 5;
#pragma unroll
    for (int k = 0; k < 5; k++) idxb[base + k] = bi[k];
  }
}

// ---------------------------------------------------------------- K3: edge MLP via MFMA
__global__ __launch_bounds__(256) void k3_edge(
    const int* __restrict__ idxb, const char* __restrict__ ewT,
    const float* __restrict__ eb, const float* __restrict__ g2,
    const float* __restrict__ b2, const float* __restrict__ m2,
    const float* __restrict__ v2, char* __restrict__ hb)
{
  int b = blockIdx.x;
  int tid = threadIdx.x;
  int w = tid >> 6, l = tid & 63;
  int lo = l & 31, hi = l >> 5;
  __shared__ _Float16 vvs[MM][136];   // pitch 272 B (68 dw == 4 mod 32: rows shift banks)
  __shared__ int idxs[MM * 5];
  char* hbb = hb + (size_t)b * HB_BATCH;

  for (int i = tid; i < MM * 5; i += 256) idxs[i] = idxb[b * MM * 5 + i];
  // zero pad row 127, ch 64..191 (bytes [128,384)) for k4
  if (tid < 16) *(float4*)(hbb + 127 * HB_PITCH + 128 + tid * 16) = make_float4(0.f, 0.f, 0.f, 0.f);

  half8 af[4][4];
#pragma unroll
  for (int rt = 0; rt < 4; rt++) {
    int row = rt * 32 + lo;
    const char* rb = hbb + row * HB_PITCH;
    int sz = (row & 7) << 4;
#pragma unroll
    for (int ks = 0; ks < 4; ks++)
      af[rt][ks] = *(const half8*)(rb + ((ks * 32 + hi * 16) ^ sz));
  }
  int cu = w * 32 + lo;
  int swzW = (cu & 7) << 4;
  const char* wu = ewT + cu * 128;
  const char* wv = ewT + (128 + cu) * 128;
  half8 bu[4], bv[4];
#pragma unroll
  for (int ks = 0; ks < 4; ks++) {
    int off = (ks * 32 + hi * 16) ^ swzW;
    bu[ks] = *(const half8*)(wu + off);
    bv[ks] = *(const half8*)(wv + off);
  }
  f32x16 accu[4], accv[4];
#pragma unroll
  for (int rt = 0; rt < 4; rt++)
#pragma unroll
    for (int r = 0; r < 16; r++) { accu[rt][r] = 0.f; accv[rt][r] = 0.f; }
#pragma unroll
  for (int ks = 0; ks < 4; ks++)
#pragma unroll
    for (int rt = 0; rt < 4; rt++) {
      accu[rt] = __builtin_amdgcn_mfma_f32_32x32x16_f16(af[rt][ks], bu[ks], accu[rt], 0, 0, 0);
      accv[rt] = __builtin_amdgcn_mfma_f32_32x32x16_f16(af[rt][ks], bv[ks], accv[rt], 0, 0, 0);
    }
#pragma unroll
  for (int rt = 0; rt < 4; rt++)
#pragma unroll
    for (int r = 0; r < 16; r++) {
      int p = rt * 32 + (r & 3) + 8 * (r >> 2) + 4 * hi;
      if (p < MM) vvs[p][cu] = (_Float16)accv[rt][r];
    }
  __syncthreads();
  float ebv = eb[cu];
  float s2 = g2[cu] * rsqrtf(v2[cu] + EPS);
  float t2 = b2[cu] - m2[cu] * s2;
#pragma unroll
  for (int rt = 0; rt < 4; rt++)
#pragma unroll
    for (int r = 0; r < 16; r++) {
      int p = rt * 32 + (r & 3) + 8 * (r >> 2) + 4 * hi;
      if (p >= MM) continue;
      const int* ip = &idxs[p * 5];
      float u = accu[rt][r];
      float mx = -1e30f;
#pragma unroll
      for (int k = 0; k < 5; k++)
        mx = fmaxf(mx, u + (float)vvs[ip[k]][cu]);
      float o = fmaxf(mx + ebv, 0.f) * s2 + t2;
      *(_Float16*)(hbb + p * HB_PITCH + ((128 + 2 * cu) ^ ((p & 7) << 4))) = (_Float16)o;
    }
}

// ---------------------------------------------------------------- K4: lin1 via MFMA + max over M
// v4: 512 thr / 8 waves = (row-half rh) x (col-quarter cq). Wave holds ONLY its
// 2 row-tiles' A-frags (af[2][12], 96 regs) reused across 8 col-tiles; B-frags
// from global lwT (L2-resident) with 1-deep register prefetch (bf[2][12], 96).
// acc[2] (32) -> ~244 VGPR, fits 2 waves/SIMD. No main-loop barriers.
// Row-max spans the two rh waves -> rmslab LDS combine + bn3.
__global__ __launch_bounds__(512, 2) void k4_lin1(
    const char* __restrict__ hb, const char* __restrict__ lwT,
    const float* __restrict__ lb, const float* __restrict__ g3,
    const float* __restrict__ b3, const float* __restrict__ m3,
    const float* __restrict__ v3, float* __restrict__ gout)
{
  int b = blockIdx.x;
  int tid = threadIdx.x;
  int w = tid >> 6;
  int rh = w >> 2, cq = w & 3;
  int l = tid & 63;
  int lo = l & 31, hi = l >> 5;
  __shared__ __align__(16) char sA[HB_BATCH];   // 48 KB
  __shared__ float rmslab[2][1024];             // 8 KB

  {
    const char* gA = hb + (size_t)b * HB_BATCH;
#pragma unroll
    for (int i = 0; i < 6; i++)
      *(float4*)(sA + (i * 512 + tid) * 16) = *(const float4*)(gA + (i * 512 + tid) * 16);
  }
  __syncthreads();

  // A-fragments for this wave's 2 row-tiles (rt = rh*2 + q)
  int sz = (lo & 7) << 4;
  half8 af[2][12];
#pragma unroll
  for (int q = 0; q < 2; q++) {
    const char* rbase = sA + ((rh * 2 + q) * 32 + lo) * HB_PITCH;
#pragma unroll
    for (int ks = 0; ks < 12; ks++)
      af[q][ks] = *(const half8*)(rbase + ((ks * 32 + hi * 16) ^ sz));
  }

  int col0 = cq * 256 + lo;   // this wave's first col-tile column (per-lane)
  half8 bf[2][12];
  {
    const char* cb0 = lwT + (size_t)col0 * HB_PITCH;
#pragma unroll
    for (int ks = 0; ks < 12; ks++)
      bf[0][ks] = *(const half8*)(cb0 + ((ks * 32 + hi * 16) ^ sz));
  }
#pragma unroll
  for (int ct = 0; ct < 8; ct++) {
    if (ct < 7) {
      const char* cbn = lwT + (size_t)(col0 + (ct + 1) * 32) * HB_PITCH;
#pragma unroll
      for (int ks = 0; ks < 12; ks++)
        bf[(ct + 1) & 1][ks] = *(const half8*)(cbn + ((ks * 32 + hi * 16) ^ sz));
    }
    f32x16 acc[2];
#pragma unroll
    for (int q = 0; q < 2; q++)
#pragma unroll
      for (int r = 0; r < 16; r++) acc[q][r] = 0.f;
#pragma unroll
    for (int ks = 0; ks < 12; ks++) {
      acc[0] = __builtin_amdgcn_mfma_f32_32x32x16_f16(af[0][ks], bf[ct & 1][ks], acc[0], 0, 0, 0);
      acc[1] = __builtin_amdgcn_mfma_f32_32x32x16_f16(af[1][ks], bf[ct & 1][ks], acc[1], 0, 0, 0);
    }
    int col = col0 + ct * 32;
    float bias = lb[col];
    float rm = 0.f;
#pragma unroll
    for (int q = 0; q < 2; q++)
#pragma unroll
      for (int r = 0; r < 16; r++) {
        float v = fmaxf(acc[q][r] + bias, 0.f);
        if (q == 1 && r == 15) v = (rh == 1 && hi == 1) ? 0.f : v;  // global row 127 = pad
        rm = fmaxf(rm, v);
      }
    rm = fmaxf(rm, __shfl_xor(rm, 32));
    if (hi == 0) rmslab[rh][col] = rm;
  }
  __syncthreads();
  if (tid < 256) {
#pragma unroll
    for (int j = 0; j < 4; j++) {
      int c = tid * 4 + j;
      float mv = fmaxf(rmslab[0][c], rmslab[1][c]);
      float s = g3[c] * rsqrtf(v3[c] + EPS);
      float t = b3[c] - m3[c] * s;
      gout[b * 1024 + c] = mv * s + t;
    }
  }
}

// ---------------------------------------------------------------- K5: head MLP layers
__global__ __launch_bounds__(256) void k5_mlp(
    const float* __restrict__ in, const float* __restrict__ w,
    const float* __restrict__ bias, const float* __restrict__ gg,
    const float* __restrict__ bbp, const float* __restrict__ mmp,
    const float* __restrict__ vvp, float* __restrict__ out,
    int K, int N, int ctiles)
{
  int bid = blockIdx.x;
  int rg = bid / ctiles, ct = bid % ctiles;
  int tid = threadIdx.x;
  int c = tid & 127, rh = tid >> 7;
  int col = ct * 128 + c;
  extern __shared__ float grows[];
  for (int i = tid; i < 4 * K; i += 256) grows[i] = in[rg * 4 * K + i];
  __syncthreads();
  float acc0 = 0.f, acc1 = 0.f;
  for (int d4 = 0; d4 < K / 4; d4++) {
    float4 ga = *reinterpret_cast<const float4*>(&grows[rh * K + d4 * 4]);
    float4 gb = *reinterpret_cast<const float4*>(&grows[(rh + 2) * K + d4 * 4]);
    float gaa[4] = {ga.x, ga.y, ga.z, ga.w};
    float gba[4] = {gb.x, gb.y, gb.z, gb.w};
#pragma unroll
    for (int dd = 0; dd < 4; dd++) {
      float wv = w[(d4 * 4 + dd) * N + col];
      acc0 = fmaf(gaa[dd], wv, acc0);
      acc1 = fmaf(gba[dd], wv, acc1);
    }
  }
  float s = gg[col] * rsqrtf(vvp[col] + EPS);
  float t = bbp[col] - mmp[col] * s;
  float bv = bias[col];
  int r0 = rg * 4;
  out[(r0 + rh) * N + col] = fmaxf(acc0 + bv, 0.f) * s + t;
  out[(r0 + rh + 2) * N + col] = fmaxf(acc1 + bv, 0.f) * s + t;
}

// ---------------------------------------------------------------- K5c: final 256->2
__global__ __launch_bounds__(256) void k5c_out(
    const float* __restrict__ c2, const float* __restrict__ ow,
    const float* __restrict__ ob, float* __restrict__ out)
{
  int t = blockIdx.x * 256 + threadIdx.x;
  int r = t >> 1, c = t & 1;
  float acc = 0.f;
  for (int d = 0; d < 256; d++) acc = fmaf(c2[r * 256 + d], ow[d * 2 + c], acc);
  out[t] = acc + ob[c];
}

extern "C" void kernel_launch(void* const* d_in, const int* in_sizes, int n_in,
                              void* d_out, int out_size, void* d_ws, size_t ws_size,
                              hipStream_t stream)
{
  const float* pos = (const float*)d_in[0];
  const float* cw  = (const float*)d_in[4];
  const float* cb  = (const float*)d_in[5];
  const float* g1  = (const float*)d_in[6];
  const float* b1  = (const float*)d_in[7];
  const float* m1  = (const float*)d_in[8];
  const float* v1  = (const float*)d_in[9];
  const float* ew  = (const float*)d_in[10];
  const float* eb  = (const float*)d_in[11];
  const float* g2  = (const float*)d_in[12];
  const float* b2  = (const float*)d_in[13];
  const float* m2  = (const float*)d_in[14];
  const float* v2  = (const float*)d_in[15];
  const float* lw  = (const float*)d_in[16];
  const float* lb  = (const float*)d_in[17];
  const float* g3  = (const float*)d_in[18];
  const float* b3  = (const float*)d_in[19];
  const float* m3  = (const float*)d_in[20];
  const float* v3  = (const float*)d_in[21];
  const float* m1w = (const float*)d_in[22];
  const float* m1b = (const float*)d_in[23];
  const float* g4  = (const float*)d_in[24];
  const float* b4  = (const float*)d_in[25];
  const float* m4  = (const float*)d_in[26];
  const float* v4  = (const float*)d_in[27];
  const float* m2w = (const float*)d_in[28];
  const float* m2b = (const float*)d_in[29];
  const float* g5  = (const float*)d_in[30];
  const float* b5  = (const float*)d_in[31];
  const float* m5  = (const float*)d_in[32];
  const float* v5  = (const float*)d_in[33];
  const float* ow  = (const float*)d_in[34];
  const float* ob  = (const float*)d_in[35];

  char* ws = (char*)d_ws;
  float* xg   = (float*)(ws);              // 512*127*64 f32      = 16,646,144 B
  char*  hb   = ws + 16646144;             // 512*128*192 f16 swz = 25,165,824 B
  char*  lwT  = ws + 41811968;             // 1024*192 f16 swz    =    393,216 B
  char*  ewT  = ws + 42205184;             // 256*64 f16 swz      =     32,768 B
  int*   idxb = (int*)(ws + 42237952);     // 512*127*5 i32       =  1,300,480 B
  float* gbuf = (float*)(ws + 43538432);   // 512*1024 f32        =  2,097,152 B
  float* c1   = (float*)(ws + 45635584);   // 512*512 f32         =  1,048,576 B
  float* c2   = (float*)(ws + 46684160);   // 512*256 f32         =    524,288 B

  hipLaunchKernelGGL(k0_prep, dim3(33), dim3(256), 0, stream, lw, lwT, ew, ewT);
  hipLaunchKernelGGL(k1_conv, dim3(512), dim3(256), 0, stream,
                     pos, cw, cb, g1, b1, m1, v1, xg, hb);
  hipLaunchKernelGGL(k2_knn, dim3(512), dim3(128), 0, stream, xg, idxb);
  hipLaunchKernelGGL(k3_edge, dim3(512), dim3(256), 0, stream,
                     idxb, ewT, eb, g2, b2, m2, v2, hb);
  hipLaunchKernelGGL(k4_lin1, dim3(512), dim3(512), 0, stream,
                     hb, lwT, lb, g3, b3, m3, v3, gbuf);
  hipLaunchKernelGGL(k5_mlp, dim3(512), dim3(256), 4 * 1024 * 4, stream,
                     gbuf, m1w, m1b, g4, b4, m4, v4, c1, 1024, 512, 4);
  hipLaunchKernelGGL(k5_mlp, dim3(256), dim3(256), 4 * 512 * 4, stream,
                     c1, m2w, m2b, g5, b5, m5, v5, c2, 512, 256, 2);
  hipLaunchKernelGGL(k5c_out, dim3(4), dim3(256), 0, stream,
                     c2, ow, ob, (float*)d_out);
}

// Round 6
// 133.780 us; speedup vs baseline: 2.0395x; 1.6919x over previous
//
#include <hip/hip_runtime.h>

#define BB 512
#define LL 128
#define MM 127
#define EPS 1e-5f

typedef _Float16 half4 __attribute__((ext_vector_type(4)));
typedef _Float16 half8 __attribute__((ext_vector_type(8)));
typedef float f32x16 __attribute__((ext_vector_type(16)));

// hb layout: per batch b: 128 rows x 192 ch fp16, row pitch 384 B,
// in-row byte offset = (2*ch) ^ ((row&7)<<4)   (XOR swizzle, G4)
#define HB_PITCH 384
#define HB_BATCH 49152

// ---------------------------------------------------------------- K0: weight prep
// 0..31:  lwT[col][k] fp16 swz (lin1_w^T, pitch 384)
// 32:     ewT[col][k] fp16 swz (cols 0..127 = wd = top-bot, 128..255 = wb)
// 33..96: m1wT[col][k] fp16 swz (m1_w^T 512x1024, pitch 2048)
// 97..112:m2wT[col][k] fp16 swz (m2_w^T 256x512,  pitch 1024)
__global__ __launch_bounds__(256) void k0_prep(
    const float* __restrict__ lw, char* __restrict__ lwT,
    const float* __restrict__ ew, char* __restrict__ ewT,
    const float* __restrict__ m1w, char* __restrict__ m1wT,
    const float* __restrict__ m2w, char* __restrict__ m2wT)
{
  int tid = threadIdx.x;
  __shared__ float ws2[256][32];   // shared by the two transpose branches
  if (blockIdx.x < 32) {
    int c0 = blockIdx.x * 32;
    __shared__ float wcol[192][32];
    for (int i = tid; i < 192 * 32; i += 256) {
      int k = i >> 5, c = i & 31;
      wcol[k][c] = lw[k * 1024 + c0 + c];
    }
    __syncthreads();
    for (int j = tid; j < 768; j += 256) {
      int kg = j >> 5, c = j & 31;
      half8 v;
#pragma unroll
      for (int jj = 0; jj < 8; jj++) v[jj] = (_Float16)wcol[kg * 8 + jj][c];
      int cc = c0 + c;
      *(half8*)(lwT + cc * HB_PITCH + ((kg * 16) ^ ((cc & 7) << 4))) = v;
    }
  } else if (blockIdx.x == 32) {
    __shared__ float es[128][128];
    for (int i = tid; i < 128 * 128; i += 256) es[i >> 7][i & 127] = ew[i];
    __syncthreads();
    for (int i = tid; i < 256 * 8; i += 256) {
      int c = i >> 3, kg = i & 7;
      half8 v;
#pragma unroll
      for (int jj = 0; jj < 8; jj++) {
        int k = kg * 8 + jj;
        float val = (c < 128) ? (es[k][c] - es[64 + k][c]) : es[64 + k][c - 128];
        v[jj] = (_Float16)val;
      }
      *(half8*)(ewT + c * 128 + ((kg * 16) ^ ((c & 7) << 4))) = v;
    }
  } else {
    const float* src; char* dst; int N, K, c0, k0;
    if (blockIdx.x < 97) {
      int bb = blockIdx.x - 33;
      src = m1w; dst = m1wT; N = 512; K = 1024;
      c0 = (bb >> 2) * 32; k0 = (bb & 3) * 256;
    } else {
      int bb = blockIdx.x - 97;
      src = m2w; dst = m2wT; N = 256; K = 512;
      c0 = (bb >> 1) * 32; k0 = (bb & 1) * 256;
    }
    for (int i = tid; i < 256 * 32; i += 256) {
      int k = i >> 5, c = i & 31;
      ws2[k][c] = src[(size_t)(k0 + k) * N + c0 + c];
    }
    __syncthreads();
    for (int j = tid; j < 32 * 32; j += 256) {
      int kg = j >> 5, c = j & 31;
      half8 v;
#pragma unroll
      for (int jj = 0; jj < 8; jj++) v[jj] = (_Float16)ws2[kg * 8 + jj][c];
      int cc = c0 + c;
      *(half8*)(dst + (size_t)cc * (2 * K) + ((2 * (k0 + kg * 8)) ^ ((cc & 7) << 4))) = v;
    }
  }
}

// ---------------------------------------------------------------- K1: conv1d
__global__ __launch_bounds__(256) void k1_conv(
    const float* __restrict__ pos, const float* __restrict__ cw,
    const float* __restrict__ cb, const float* __restrict__ g1,
    const float* __restrict__ b1, const float* __restrict__ m1,
    const float* __restrict__ v1, float* __restrict__ xg,
    char* __restrict__ hb)
{
  int b = blockIdx.x;
  int tid = threadIdx.x;
  __shared__ float ps[LL * 3];
  __shared__ float fpad[MM + 4][6];
  __shared__ float ws[5 * 6 * 64];
  __shared__ float s1s[64], t1s[64];
  for (int i = tid; i < LL * 3; i += 256) ps[i] = pos[b * LL * 3 + i];
  for (int i = tid; i < 5 * 6 * 64; i += 256) ws[i] = cw[i];
  if (tid < 64) {
    float s = g1[tid] * rsqrtf(v1[tid] + EPS);
    s1s[tid] = s;
    t1s[tid] = (cb[tid] - m1[tid]) * s + b1[tid];
  }
  if (tid < 24) {
    int r = tid / 6, c = tid % 6;
    int rr = (r < 2) ? r : (MM + r);
    fpad[rr][c] = 0.f;
  }
  __syncthreads();
  for (int i = tid; i < MM * 6; i += 256) {
    int m = i / 6, c = i % 6;
    float v = (c < 3) ? (ps[(m + 1) * 3 + c] - ps[m * 3 + c]) : ps[m * 3 + c - 3];
    fpad[m + 2][c] = v;
  }
  __syncthreads();
  int orow = BB - 1 - b;
  char* hbb = hb + (size_t)orow * HB_BATCH;
  if (tid < 8) *(float4*)(hbb + 127 * HB_PITCH + tid * 16) = make_float4(0.f, 0.f, 0.f, 0.f);
  for (int o = tid; o < MM * 64; o += 256) {
    int m = o >> 6, c = o & 63;
    float af = 0.f, ab = 0.f;
#pragma unroll
    for (int t = 0; t < 5; t++) {
#pragma unroll
      for (int ci = 0; ci < 6; ci++) {
        float wv = ws[(t * 6 + ci) * 64 + c];
        af = fmaf(fpad[m + t][ci], wv, af);
        ab = fmaf(fpad[m + 4 - t][ci], wv, ab);
      }
    }
    float z = fmaxf(af, ab) * s1s[c] + t1s[c];
    float xv = fmaxf(z, 0.f);
    int p = MM - 1 - m;
    xg[(orow * MM + p) * 64 + c] = xv;
    *(_Float16*)(hbb + p * HB_PITCH + ((2 * c) ^ ((p & 7) << 4))) = (_Float16)xv;
  }
}

// ---------------------------------------------------------------- K2: kNN top-5
// v2: 256 thr = (j-half g) x (row). float4 LDS reads; per-group top-5 then
// sorted 5+5 merge. Distances fp32 (top-k ordering is discrete).
__global__ __launch_bounds__(256) void k2_knn(
    const float* __restrict__ xg, int* __restrict__ idxb)
{
  int b = blockIdx.x;
  int tid = threadIdx.x;
  int g = tid >> 7, row = tid & 127;
  __shared__ float4 xs4[MM][16];
  __shared__ float sq[MM];
  __shared__ float bsl[2][128][5];
  __shared__ int   bil[2][128][5];
  const float4* src = (const float4*)(xg + b * MM * 64);
  for (int i = tid; i < MM * 16; i += 256) xs4[i >> 4][i & 15] = src[i];
  __syncthreads();
  float4 xm4[16];
  if (row < MM) {
    float s = 0.f;
#pragma unroll
    for (int d4 = 0; d4 < 16; d4++) {
      xm4[d4] = xs4[row][d4];
      s = fmaf(xm4[d4].x, xm4[d4].x, s);
      s = fmaf(xm4[d4].y, xm4[d4].y, s);
      s = fmaf(xm4[d4].z, xm4[d4].z, s);
      s = fmaf(xm4[d4].w, xm4[d4].w, s);
    }
    if (g == 0) sq[row] = s;
  }
  __syncthreads();
  float bs[5]; int bi[5];
#pragma unroll
  for (int k = 0; k < 5; k++) { bs[k] = 1e30f; bi[k] = 0; }
  if (row < MM) {
    int j0 = g * 64;
    int j1 = g ? MM : 64;
    for (int j = j0; j < j1; j++) {
      float dot = 0.f;
#pragma unroll
      for (int d4 = 0; d4 < 16; d4++) {
        float4 xv = xs4[j][d4];
        dot = fmaf(xm4[d4].x, xv.x, dot);
        dot = fmaf(xm4[d4].y, xv.y, dot);
        dot = fmaf(xm4[d4].z, xv.z, dot);
        dot = fmaf(xm4[d4].w, xv.w, dot);
      }
      float sc = sq[j] - 2.f * dot;
      if (sc < bs[4]) {
        bs[4] = sc; bi[4] = j;
#pragma unroll
        for (int k = 3; k >= 0; k--) {
          if (bs[k + 1] < bs[k]) {
            float ts = bs[k]; bs[k] = bs[k + 1]; bs[k + 1] = ts;
            int ti = bi[k]; bi[k] = bi[k + 1]; bi[k + 1] = ti;
          }
        }
      }
    }
  }
#pragma unroll
  for (int k = 0; k < 5; k++) { bsl[g][row][k] = bs[k]; bil[g][row][k] = bi[k]; }
  __syncthreads();
  if (tid < MM) {
    int i0 = 0, i1 = 0;
    int base = (b * MM + tid) * 5;
#pragma unroll
    for (int k = 0; k < 5; k++) {
      float v0 = bsl[0][tid][i0], v1 = bsl[1][tid][i1];
      int id;
      if (v0 <= v1) { id = bil[0][tid][i0]; i0++; }
      else          { id = bil[1][tid][i1]; i1++; }
      idxb[base + k] = id;
    }
  }
}

// ---------------------------------------------------------------- K3: edge MLP via MFMA
__global__ __launch_bounds__(256) void k3_edge(
    const int* __restrict__ idxb, const char* __restrict__ ewT,
    const float* __restrict__ eb, const float* __restrict__ g2,
    const float* __restrict__ b2, const float* __restrict__ m2,
    const float* __restrict__ v2, char* __restrict__ hb)
{
  int b = blockIdx.x;
  int tid = threadIdx.x;
  int w = tid >> 6, l = tid & 63;
  int lo = l & 31, hi = l >> 5;
  __shared__ _Float16 vvs[MM][136];
  __shared__ int idxs[MM * 5];
  char* hbb = hb + (size_t)b * HB_BATCH;

  for (int i = tid; i < MM * 5; i += 256) idxs[i] = idxb[b * MM * 5 + i];
  if (tid < 16) *(float4*)(hbb + 127 * HB_PITCH + 128 + tid * 16) = make_float4(0.f, 0.f, 0.f, 0.f);

  half8 af[4][4];
#pragma unroll
  for (int rt = 0; rt < 4; rt++) {
    int row = rt * 32 + lo;
    const char* rb = hbb + row * HB_PITCH;
    int sz = (row & 7) << 4;
#pragma unroll
    for (int ks = 0; ks < 4; ks++)
      af[rt][ks] = *(const half8*)(rb + ((ks * 32 + hi * 16) ^ sz));
  }
  int cu = w * 32 + lo;
  int swzW = (cu & 7) << 4;
  const char* wu = ewT + cu * 128;
  const char* wv = ewT + (128 + cu) * 128;
  half8 bu[4], bv[4];
#pragma unroll
  for (int ks = 0; ks < 4; ks++) {
    int off = (ks * 32 + hi * 16) ^ swzW;
    bu[ks] = *(const half8*)(wu + off);
    bv[ks] = *(const half8*)(wv + off);
  }
  f32x16 accu[4], accv[4];
#pragma unroll
  for (int rt = 0; rt < 4; rt++)
#pragma unroll
    for (int r = 0; r < 16; r++) { accu[rt][r] = 0.f; accv[rt][r] = 0.f; }
#pragma unroll
  for (int ks = 0; ks < 4; ks++)
#pragma unroll
    for (int rt = 0; rt < 4; rt++) {
      accu[rt] = __builtin_amdgcn_mfma_f32_32x32x16_f16(af[rt][ks], bu[ks], accu[rt], 0, 0, 0);
      accv[rt] = __builtin_amdgcn_mfma_f32_32x32x16_f16(af[rt][ks], bv[ks], accv[rt], 0, 0, 0);
    }
#pragma unroll
  for (int rt = 0; rt < 4; rt++)
#pragma unroll
    for (int r = 0; r < 16; r++) {
      int p = rt * 32 + (r & 3) + 8 * (r >> 2) + 4 * hi;
      if (p < MM) vvs[p][cu] = (_Float16)accv[rt][r];
    }
  __syncthreads();
  float ebv = eb[cu];
  float s2 = g2[cu] * rsqrtf(v2[cu] + EPS);
  float t2 = b2[cu] - m2[cu] * s2;
#pragma unroll
  for (int rt = 0; rt < 4; rt++)
#pragma unroll
    for (int r = 0; r < 16; r++) {
      int p = rt * 32 + (r & 3) + 8 * (r >> 2) + 4 * hi;
      if (p >= MM) continue;
      const int* ip = &idxs[p * 5];
      float u = accu[rt][r];
      float mx = -1e30f;
#pragma unroll
      for (int k = 0; k < 5; k++)
        mx = fmaxf(mx, u + (float)vvs[ip[k]][cu]);
      float o = fmaxf(mx + ebv, 0.f) * s2 + t2;
      *(_Float16*)(hbb + p * HB_PITCH + ((128 + 2 * cu) ^ ((p & 7) << 4))) = (_Float16)o;
    }
}

// ---------------------------------------------------------------- K4: lin1 via MFMA + max over M
// 512 thr / 8 waves = (row-half rh) x (col-quarter cq); af[2][12] reused
// across 8 col-tiles; bf from global lwT with 1-deep prefetch; rmslab combine.
// Epilogue now emits gbufh fp16 swizzled (pitch 2048) for k5_gemm.
__global__ __launch_bounds__(512, 2) void k4_lin1(
    const char* __restrict__ hb, const char* __restrict__ lwT,
    const float* __restrict__ lb, const float* __restrict__ g3,
    const float* __restrict__ b3, const float* __restrict__ m3,
    const float* __restrict__ v3, char* __restrict__ gbufh)
{
  int b = blockIdx.x;
  int tid = threadIdx.x;
  int w = tid >> 6;
  int rh = w >> 2, cq = w & 3;
  int l = tid & 63;
  int lo = l & 31, hi = l >> 5;
  __shared__ __align__(16) char sA[HB_BATCH];   // 48 KB
  __shared__ float rmslab[2][1024];             // 8 KB

  {
    const char* gA = hb + (size_t)b * HB_BATCH;
#pragma unroll
    for (int i = 0; i < 6; i++)
      *(float4*)(sA + (i * 512 + tid) * 16) = *(const float4*)(gA + (i * 512 + tid) * 16);
  }
  __syncthreads();

  int sz = (lo & 7) << 4;
  half8 af[2][12];
#pragma unroll
  for (int q = 0; q < 2; q++) {
    const char* rbase = sA + ((rh * 2 + q) * 32 + lo) * HB_PITCH;
#pragma unroll
    for (int ks = 0; ks < 12; ks++)
      af[q][ks] = *(const half8*)(rbase + ((ks * 32 + hi * 16) ^ sz));
  }

  int col0 = cq * 256 + lo;
  half8 bf[2][12];
  {
    const char* cb0 = lwT + (size_t)col0 * HB_PITCH;
#pragma unroll
    for (int ks = 0; ks < 12; ks++)
      bf[0][ks] = *(const half8*)(cb0 + ((ks * 32 + hi * 16) ^ sz));
  }
#pragma unroll
  for (int ct = 0; ct < 8; ct++) {
    if (ct < 7) {
      const char* cbn = lwT + (size_t)(col0 + (ct + 1) * 32) * HB_PITCH;
#pragma unroll
      for (int ks = 0; ks < 12; ks++)
        bf[(ct + 1) & 1][ks] = *(const half8*)(cbn + ((ks * 32 + hi * 16) ^ sz));
    }
    f32x16 acc[2];
#pragma unroll
    for (int q = 0; q < 2; q++)
#pragma unroll
      for (int r = 0; r < 16; r++) acc[q][r] = 0.f;
#pragma unroll
    for (int ks = 0; ks < 12; ks++) {
      acc[0] = __builtin_amdgcn_mfma_f32_32x32x16_f16(af[0][ks], bf[ct & 1][ks], acc[0], 0, 0, 0);
      acc[1] = __builtin_amdgcn_mfma_f32_32x32x16_f16(af[1][ks], bf[ct & 1][ks], acc[1], 0, 0, 0);
    }
    int col = col0 + ct * 32;
    float bias = lb[col];
    float rm = 0.f;
#pragma unroll
    for (int q = 0; q < 2; q++)
#pragma unroll
      for (int r = 0; r < 16; r++) {
        float v = fmaxf(acc[q][r] + bias, 0.f);
        if (q == 1 && r == 15) v = (rh == 1 && hi == 1) ? 0.f : v;
        rm = fmaxf(rm, v);
      }
    rm = fmaxf(rm, __shfl_xor(rm, 32));
    if (hi == 0) rmslab[rh][col] = rm;
  }
  __syncthreads();
  if (tid < 256) {
    half4 o;
#pragma unroll
    for (int j = 0; j < 4; j++) {
      int c = tid * 4 + j;
      float mv = fmaxf(rmslab[0][c], rmslab[1][c]);
      float s = g3[c] * rsqrtf(v3[c] + EPS);
      float t = b3[c] - m3[c] * s;
      o[j] = (_Float16)(mv * s + t);
    }
    *(half4*)(gbufh + (size_t)b * 2048 + ((8 * tid) ^ ((b & 7) << 4))) = o;
  }
}

// ---------------------------------------------------------------- K5: head MLP via MFMA
// Block = 1 wave, 32x32 output tile. K streamed in 128-chunks, register
// double-buffered from global (L2-resident). out = relu(acc+bias)*s + t;
// stores fp16 swizzled (outh, pitch 2N) or f32 plain (outf).
template<int K, int N>
__global__ __launch_bounds__(64) void k5_gemm(
    const char* __restrict__ inh, const char* __restrict__ wT,
    const float* __restrict__ bias, const float* __restrict__ gg,
    const float* __restrict__ bbp, const float* __restrict__ mmp,
    const float* __restrict__ vvp, char* __restrict__ outh,
    float* __restrict__ outf)
{
  constexpr int NT = N / 32;
  constexpr int NC = K / 128;
  int bid = blockIdx.x;
  int mt = bid / NT, nt = bid % NT;
  int l = threadIdx.x;
  int lo = l & 31, hi = l >> 5;
  int row = mt * 32 + lo, col = nt * 32 + lo;
  const char* arow = inh + (size_t)row * (2 * K);
  const char* brow = wT + (size_t)col * (2 * K);
  int sza = (row & 7) << 4, szb = (col & 7) << 4;

  half8 a[2][8], bf[2][8];
#pragma unroll
  for (int ks = 0; ks < 8; ks++) {
    int off = ks * 32 + hi * 16;
    a[0][ks]  = *(const half8*)(arow + (off ^ sza));
    bf[0][ks] = *(const half8*)(brow + (off ^ szb));
  }
  f32x16 acc;
#pragma unroll
  for (int r = 0; r < 16; r++) acc[r] = 0.f;
#pragma unroll
  for (int c = 0; c < NC; c++) {
    if (c + 1 < NC) {
#pragma unroll
      for (int ks = 0; ks < 8; ks++) {
        int off = (c + 1) * 256 + ks * 32 + hi * 16;
        a[(c + 1) & 1][ks]  = *(const half8*)(arow + (off ^ sza));
        bf[(c + 1) & 1][ks] = *(const half8*)(brow + (off ^ szb));
      }
    }
#pragma unroll
    for (int ks = 0; ks < 8; ks++)
      acc = __builtin_amdgcn_mfma_f32_32x32x16_f16(a[c & 1][ks], bf[c & 1][ks], acc, 0, 0, 0);
  }
  float bv = bias[col];
  float s = gg[col] * rsqrtf(vvp[col] + EPS);
  float t = bbp[col] - mmp[col] * s;
#pragma unroll
  for (int r = 0; r < 16; r++) {
    float z = fmaxf(acc[r] + bv, 0.f) * s + t;
    int orow = mt * 32 + (r & 3) + 8 * (r >> 2) + 4 * hi;
    if (outh)
      *(_Float16*)(outh + (size_t)orow * (2 * N) + ((2 * col) ^ ((orow & 7) << 4))) = (_Float16)z;
    else
      outf[(size_t)orow * N + col] = z;
  }
}

// ---------------------------------------------------------------- K5c: final 256->2
__global__ __launch_bounds__(256) void k5c_out(
    const float* __restrict__ c2, const float* __restrict__ ow,
    const float* __restrict__ ob, float* __restrict__ out)
{
  int t = blockIdx.x * 256 + threadIdx.x;
  int r = t >> 1, c = t & 1;
  float acc = 0.f;
  for (int d4 = 0; d4 < 64; d4++) {
    float4 cv = *(const float4*)(c2 + r * 256 + d4 * 4);
    acc = fmaf(cv.x, ow[(d4 * 4 + 0) * 2 + c], acc);
    acc = fmaf(cv.y, ow[(d4 * 4 + 1) * 2 + c], acc);
    acc = fmaf(cv.z, ow[(d4 * 4 + 2) * 2 + c], acc);
    acc = fmaf(cv.w, ow[(d4 * 4 + 3) * 2 + c], acc);
  }
  out[t] = acc + ob[c];
}

extern "C" void kernel_launch(void* const* d_in, const int* in_sizes, int n_in,
                              void* d_out, int out_size, void* d_ws, size_t ws_size,
                              hipStream_t stream)
{
  const float* pos = (const float*)d_in[0];
  const float* cw  = (const float*)d_in[4];
  const float* cb  = (const float*)d_in[5];
  const float* g1  = (const float*)d_in[6];
  const float* b1  = (const float*)d_in[7];
  const float* m1  = (const float*)d_in[8];
  const float* v1  = (const float*)d_in[9];
  const float* ew  = (const float*)d_in[10];
  const float* eb  = (const float*)d_in[11];
  const float* g2  = (const float*)d_in[12];
  const float* b2  = (const float*)d_in[13];
  const float* m2  = (const float*)d_in[14];
  const float* v2  = (const float*)d_in[15];
  const float* lw  = (const float*)d_in[16];
  const float* lb  = (const float*)d_in[17];
  const float* g3  = (const float*)d_in[18];
  const float* b3  = (const float*)d_in[19];
  const float* m3  = (const float*)d_in[20];
  const float* v3  = (const float*)d_in[21];
  const float* m1w = (const float*)d_in[22];
  const float* m1b = (const float*)d_in[23];
  const float* g4  = (const float*)d_in[24];
  const float* b4  = (const float*)d_in[25];
  const float* m4  = (const float*)d_in[26];
  const float* v4  = (const float*)d_in[27];
  const float* m2w = (const float*)d_in[28];
  const float* m2b = (const float*)d_in[29];
  const float* g5  = (const float*)d_in[30];
  const float* b5  = (const float*)d_in[31];
  const float* m5  = (const float*)d_in[32];
  const float* v5  = (const float*)d_in[33];
  const float* ow  = (const float*)d_in[34];
  const float* ob  = (const float*)d_in[35];

  char* ws = (char*)d_ws;
  float* xg    = (float*)(ws);             // 512*127*64 f32      = 16,646,144 B
  char*  hb    = ws + 16646144;            // 512*128*192 f16 swz = 25,165,824 B
  char*  lwT   = ws + 41811968;            // 1024*192 f16 swz    =    393,216 B
  char*  ewT   = ws + 42205184;            // 256*64 f16 swz      =     32,768 B
  int*   idxb  = (int*)(ws + 42237952);    // 512*127*5 i32       =  1,300,480 B
  char*  gbufh = ws + 43538432;            // 512*1024 f16 swz    =  1,048,576 B
  char*  m1wT  = ws + 44587008;            // 512*1024 f16 swz    =  1,048,576 B
  char*  c1h   = ws + 45635584;            // 512*512 f16 swz     =    524,288 B
  char*  m2wT  = ws + 46159872;            // 256*512 f16 swz     =    262,144 B
  float* c2    = (float*)(ws + 46422016);  // 512*256 f32         =    524,288 B

  hipLaunchKernelGGL(k0_prep, dim3(113), dim3(256), 0, stream,
                     lw, lwT, ew, ewT, m1w, m1wT, m2w, m2wT);
  hipLaunchKernelGGL(k1_conv, dim3(512), dim3(256), 0, stream,
                     pos, cw, cb, g1, b1, m1, v1, xg, hb);
  hipLaunchKernelGGL(k2_knn, dim3(512), dim3(256), 0, stream, xg, idxb);
  hipLaunchKernelGGL(k3_edge, dim3(512), dim3(256), 0, stream,
                     idxb, ewT, eb, g2, b2, m2, v2, hb);
  hipLaunchKernelGGL(k4_lin1, dim3(512), dim3(512), 0, stream,
                     hb, lwT, lb, g3, b3, m3, v3, gbufh);
  (k5_gemm<1024, 512>)<<<dim3(256), dim3(64), 0, stream>>>(
      gbufh, m1wT, m1b, g4, b4, m4, v4, c1h, nullptr);
  (k5_gemm<512, 256>)<<<dim3(128), dim3(64), 0, stream>>>(
      c1h, m2wT, m2b, g5, b5, m5, v5, nullptr, c2);
  hipLaunchKernelGGL(k5c_out, dim3(4), dim3(256), 0, stream,
                     c2, ow, ob, (float*)d_out);
}